// Round 8
// baseline (139.671 us; speedup 1.0000x reference)
//
#include <hip/hip_runtime.h>
#include <math.h>

#define NTOK 100
#define EDIM 5
#define NH   4
#define NL   3
#define DD   64
#define BLK  512
#define LOG2E 1.4426950408889634f

// ---------------------------------------------------------------------------
// Kernel 1: fold per-head projections into 5x5 matrices (verified r4/r6/r7).
//   M[l][h] = (1/8) * Wq^T Wk ; P[l][h] = Wv^T Wo_h^T
// ws layout: float [2][NL][NH][EDIM][8]
// ---------------------------------------------------------------------------
__global__ void precompute_mp(const float* __restrict__ Wq,
                              const float* __restrict__ Wk,
                              const float* __restrict__ Wv,
                              const float* __restrict__ Wo,
                              float* __restrict__ mp) {
  const int blk = blockIdx.x;
  const int which = blk / 12;
  const int rem = blk % 12;
  const int l = rem / 4, h = rem % 4;
  const int t = threadIdx.x;

  __shared__ float A[320];
  __shared__ float Bsh[320];

  const float* wa = (which ? Wv : Wq) + (l*NH + h)*DD*EDIM;
  for (int r = t; r < 320; r += 64) A[r] = wa[r];
  if (which == 0) {
    const float* wk = Wk + (l*NH + h)*DD*EDIM;
    for (int r = t; r < 320; r += 64) Bsh[r] = wk[r];
  } else {
    for (int r = t; r < 320; r += 64) {
      int f = r >> 6, d = r & 63;
      Bsh[r] = Wo[(l*EDIM + f)*(NH*DD) + h*DD + d];
    }
  }
  __syncthreads();
  if (t < 25) {
    int e = t / 5, f = t % 5;
    float acc = 0.f;
    if (which == 0) {
      #pragma unroll 8
      for (int d = 0; d < DD; ++d) acc += A[d*5+e] * Bsh[d*5+f];
      acc *= 0.125f;
    } else {
      #pragma unroll 8
      for (int d = 0; d < DD; ++d) acc += A[d*5+e] * Bsh[f*64+d];
    }
    mp[which*960 + ((l*NH + h)*EDIM + e)*8 + f] = acc;
  }
}

// ---------------------------------------------------------------------------
// Kernel 2: one BLOCK (512 thr, 8 waves) per batch. Wave = (head, j-half):
// each wave runs ~nm/2 j-iterations for its head; token pass combines the two
// partial (w, ls). 38KB LDS -> 4 blocks/CU = 32 waves/CU (8/SIMD) for latency
// hiding of the ds_read -> score -> v_exp -> accumulate chain.
// ---------------------------------------------------------------------------
__global__ __launch_bounds__(BLK) void encoder_kernel(
    const float* __restrict__ x,
    const float* __restrict__ mp,
    const float* __restrict__ Wf,
    const float* __restrict__ bfv,
    const float* __restrict__ g1,
    const float* __restrict__ b1,
    const float* __restrict__ g2,
    const float* __restrict__ b2,
    float* __restrict__ out)
{
  const int wv   = threadIdx.x >> 6;     // 0..7
  const int lane = threadIdx.x & 63;
  const int hd   = wv & 3;               // head
  const int jg   = wv >> 2;              // j-group (0/1)
  const int b    = blockIdx.x;

  __shared__ float s_mp[1920];           // M then P, rows [5][8]
  __shared__ float s_st[104][8];         // compacted token state
  __shared__ float s_w[2][NH][104][8];   // {w0..w4, ls} per (jgroup,head,row)
  __shared__ int   s_cidx[NTOK];

  for (int r = threadIdx.x; r < 480; r += BLK)
    ((float4*)s_mp)[r] = ((const float4*)mp)[r];

  // ---- setup: all waves compute ballots redundantly; wave 0 writes ----
  const float* xb = x + b*300;
  const int t1 = lane, t2 = lane + 64;
  float k0a = xb[3*t1], k1a = xb[3*t1+1], k2a = xb[3*t1+2];
  bool m1 = (k2a > 0.f);
  float k0b = 0.f, k1b = 0.f, k2b = 0.f; bool m2 = false;
  if (t2 < NTOK) {
    k0b = xb[3*t2]; k1b = xb[3*t2+1]; k2b = xb[3*t2+2];
    m2 = (k2b > 0.f);
  }
  unsigned long long bm1 = __ballot(m1);
  unsigned long long bm2 = __ballot(m2);
  const int pc1 = __popcll(bm1);
  const int nm  = pc1 + __popcll(bm2);   // unmasked count (uniform)
  const int ns  = nm + 1;                // + rep slot
  if (wv == 0) {
    unsigned long long below = (lane == 0) ? 0ull : ((1ull << lane) - 1ull);
    int p1 = __popcll(bm1 & below);
    int p2 = pc1 + __popcll(bm2 & below);
    if (m1) {
      *(float4*)(&s_st[p1][0]) = make_float4(k0a, k1a, k2a, sinf((float)t1));
      s_st[p1][4] = cosf((float)t1);
    }
    s_cidx[t1] = m1 ? p1 : nm;
    if (t2 < NTOK) {
      if (m2) {
        *(float4*)(&s_st[p2][0]) = make_float4(k0b, k1b, k2b, sinf((float)t2));
        s_st[p2][4] = cosf((float)t2);
      }
      s_cidx[t2] = m2 ? p2 : nm;
    }
    if (lane == 0) {
      *(float4*)(&s_st[nm][0]) = make_float4(0.f,0.f,0.f,0.f);
      s_st[nm][4] = 0.f;
    }
  }
  __syncthreads();

  const int nh2  = (ns > 64) ? 2 : 1;    // uniform across block
  const int jmid = nm >> 1;
  const int jlo  = jg ? jmid : 0;
  const int jhi  = jg ? nm : jmid;

  for (int l = 0; l < NL; ++l) {
    // ---- phase 1: wave (hd, jg) accumulates partial (w, ls) ----
    for (int half = 0; half < nh2; ++half) {
      const int row = lane + (half << 6);
      const bool active = (row < ns);
      const bool rep = (row == nm);
      const int rr = active ? row : 0;

      float4 ov = *(const float4*)(&s_st[rr][0]);
      float o[5] = {ov.x, ov.y, ov.z, ov.w, s_st[rr][4]};

      const float* Mh = s_mp + (l*NH + hd)*40;
      float a0=0.f,a1=0.f,a2=0.f,a3=0.f,a4=0.f;
      #pragma unroll
      for (int e = 0; e < 5; ++e) {
        float4 mr = *(const float4*)(Mh + e*8);
        float  m4 = Mh[e*8+4];
        a0 += o[e]*mr.x; a1 += o[e]*mr.y; a2 += o[e]*mr.z; a3 += o[e]*mr.w; a4 += o[e]*m4;
      }
      a0*=LOG2E; a1*=LOG2E; a2*=LOG2E; a3*=LOG2E; a4*=LOG2E;

      float ls=0.f, w0=0.f,w1=0.f,w2=0.f,w3=0.f,w4=0.f;
      #pragma unroll 4
      for (int j = jlo; j < jhi; ++j) {
        float4 oj = *(const float4*)(&s_st[j][0]);   // wave-uniform broadcast
        float  oe = s_st[j][4];
        float s = a0*oj.x + a1*oj.y + a2*oj.z + a3*oj.w + a4*oe;
        float p = __builtin_amdgcn_exp2f(s);
        p = rep ? 1.f : p;
        ls += p;
        w0 += p*oj.x; w1 += p*oj.y; w2 += p*oj.z; w3 += p*oj.w; w4 += p*oe;
      }
      if (active) {
        *(float4*)(&s_w[jg][hd][row][0]) = make_float4(w0, w1, w2, w3);
        *(float2*)(&s_w[jg][hd][row][4]) = make_float2(w4, ls);
      }
    }
    __syncthreads();

    // ---- phase 2: token pass on wave 0 (and wave 1 iff ns>64) ----
    if (wv < nh2) {
      const int row = lane + (wv << 6);
      const bool active = (row < ns);
      const bool rep = (row == nm);
      const int rr = active ? row : 0;

      float4 ov = *(const float4*)(&s_st[rr][0]);
      float o[5] = {ov.x, ov.y, ov.z, ov.w, s_st[rr][4]};
      float wext = rep ? (float)(NTOK - nm) : 0.f;

      float c[5] = {0.f,0.f,0.f,0.f,0.f};
      const float* Pl = s_mp + 960 + l*NH*40;
      #pragma unroll
      for (int h = 0; h < NH; ++h) {
        float4 wa = *(const float4*)(&s_w[0][h][rr][0]);
        float2 wb = *(const float2*)(&s_w[0][h][rr][4]);
        float4 wa2 = *(const float4*)(&s_w[1][h][rr][0]);
        float2 wb2 = *(const float2*)(&s_w[1][h][rr][4]);
        float w[5] = {wa.x+wa2.x, wa.y+wa2.y, wa.z+wa2.z, wa.w+wa2.w, wb.x+wb2.x};
        float inv = rep ? 0.01f : 1.f/(wb.y + wb2.y);
        const float* Ph = Pl + h*40;
        #pragma unroll
        for (int f = 0; f < 5; ++f) {
          float wn = (w[f] + wext*o[f]) * inv;
          float4 pr = *(const float4*)(Ph + f*8);
          float  p4 = Ph[f*8+4];
          c[0]+=wn*pr.x; c[1]+=wn*pr.y; c[2]+=wn*pr.z; c[3]+=wn*pr.w; c[4]+=wn*p4;
        }
      }
      float y[5];
      #pragma unroll
      for (int e = 0; e < 5; ++e) y[e] = o[e] + c[e];
      float mu = 0.2f*(y[0]+y[1]+y[2]+y[3]+y[4]);
      float var = 0.f;
      #pragma unroll
      for (int e = 0; e < 5; ++e) { float d = y[e]-mu; var += d*d; }
      var *= 0.2f;
      float inv1 = 1.f/sqrtf(var + 1e-5f);
      float ln1[5];
      #pragma unroll
      for (int e = 0; e < 5; ++e) ln1[e] = (y[e]-mu)*inv1*g1[l*5+e] + b1[l*5+e];
      float rv[5];
      #pragma unroll
      for (int e = 0; e < 5; ++e) {
        float acc = bfv[l*5+e];
        #pragma unroll
        for (int f = 0; f < 5; ++f) acc += ln1[f]*Wf[(l*5+e)*5+f];
        acc = acc > 0.f ? acc : 0.f;
        rv[e] = acc + ln1[e];
      }
      float mu2 = 0.2f*(rv[0]+rv[1]+rv[2]+rv[3]+rv[4]);
      float var2 = 0.f;
      #pragma unroll
      for (int e = 0; e < 5; ++e) { float d = rv[e]-mu2; var2 += d*d; }
      var2 *= 0.2f;
      float inv2 = 1.f/sqrtf(var2 + 1e-5f);
      float n0 = (rv[0]-mu2)*inv2*g2[l*5+0] + b2[l*5+0];
      float n1 = (rv[1]-mu2)*inv2*g2[l*5+1] + b2[l*5+1];
      float n2 = (rv[2]-mu2)*inv2*g2[l*5+2] + b2[l*5+2];
      float n3 = (rv[3]-mu2)*inv2*g2[l*5+3] + b2[l*5+3];
      float n4 = (rv[4]-mu2)*inv2*g2[l*5+4] + b2[l*5+4];
      if (active) {
        *(float4*)(&s_st[row][0]) = make_float4(n0, n1, n2, n3);
        s_st[row][4] = n4;
      }
    }
    __syncthreads();
  }

  // ---- expand compacted state back to [N, E], coalesced stores ----
  const int obase = b*(NTOK*EDIM);
  {
    int idx = threadIdx.x;
    if (idx < NTOK*EDIM) {
      int tok = idx / 5;
      int e = idx - tok*5;
      int c = s_cidx[tok];
      out[obase + idx] = s_st[c][e];
    }
  }
}

extern "C" void kernel_launch(void* const* d_in, const int* in_sizes, int n_in,
                              void* d_out, int out_size, void* d_ws, size_t ws_size,
                              hipStream_t stream) {
  const float* x  = (const float*)d_in[0];
  const float* Wq = (const float*)d_in[1];
  const float* Wk = (const float*)d_in[2];
  const float* Wv = (const float*)d_in[3];
  const float* Wo = (const float*)d_in[4];
  const float* Wf = (const float*)d_in[5];
  const float* bf = (const float*)d_in[6];
  const float* g1 = (const float*)d_in[7];
  const float* b1 = (const float*)d_in[8];
  const float* g2 = (const float*)d_in[9];
  const float* b2 = (const float*)d_in[10];
  float* outp = (float*)d_out;
  float* mp   = (float*)d_ws;   // 1920 floats

  precompute_mp<<<24, 64, 0, stream>>>(Wq, Wk, Wv, Wo, mp);
  encoder_kernel<<<1024, BLK, 0, stream>>>(x, mp, Wf, bf, g1, b1, g2, b2, outp);
}

// Round 9
// 123.301 us; speedup vs baseline: 1.1328x; 1.1328x over previous
//
#include <hip/hip_runtime.h>
#include <math.h>

#define NTOK 100
#define EDIM 5
#define NH   4
#define NL   3
#define DD   64
#define BLK  256
#define LOG2E 1.4426950408889634f
#define SCR  104   // s_c/s_st row capacity

__device__ __forceinline__ float rdlane(float v, int l) {
  return __int_as_float(__builtin_amdgcn_readlane(__float_as_int(v), l));
}

// ---------------------------------------------------------------------------
// Kernel 1: fold per-head projections into 5x5 matrices (verified r4/r6/r7).
//   M[l][h] = (1/8) * Wq^T Wk ; P[l][h] = Wv^T Wo_h^T
// ws layout: float [2][NL][NH][EDIM][8]
// ---------------------------------------------------------------------------
__global__ void precompute_mp(const float* __restrict__ Wq,
                              const float* __restrict__ Wk,
                              const float* __restrict__ Wv,
                              const float* __restrict__ Wo,
                              float* __restrict__ mp) {
  const int blk = blockIdx.x;
  const int which = blk / 12;
  const int rem = blk % 12;
  const int l = rem / 4, h = rem % 4;
  const int t = threadIdx.x;

  __shared__ float A[320];
  __shared__ float Bsh[320];

  const float* wa = (which ? Wv : Wq) + (l*NH + h)*DD*EDIM;
  for (int r = t; r < 320; r += 64) A[r] = wa[r];
  if (which == 0) {
    const float* wk = Wk + (l*NH + h)*DD*EDIM;
    for (int r = t; r < 320; r += 64) Bsh[r] = wk[r];
  } else {
    for (int r = t; r < 320; r += 64) {
      int f = r >> 6, d = r & 63;
      Bsh[r] = Wo[(l*EDIM + f)*(NH*DD) + h*DD + d];
    }
  }
  __syncthreads();
  if (t < 25) {
    int e = t / 5, f = t % 5;
    float acc = 0.f;
    if (which == 0) {
      #pragma unroll 8
      for (int d = 0; d < DD; ++d) acc += A[d*5+e] * Bsh[d*5+f];
      acc *= 0.125f;
    } else {
      #pragma unroll 8
      for (int d = 0; d < DD; ++d) acc += A[d*5+e] * Bsh[f*64+d];
    }
    mp[which*960 + ((l*NH + h)*EDIM + e)*8 + f] = acc;
  }
}

// ---------------------------------------------------------------------------
// Kernel 2: one BLOCK per batch, wave = head, lane = compacted row.
// Token state is REGISTER-resident; j-loop broadcasts row j via v_readlane
// (zero LDS in the inner loop -> no 120-cyc lgkm chains). Each wave applies
// its own head's P and writes a 5-float contribution to s_c (stride-7,
// conflict-free); all waves redundantly run the token pass in fixed head
// order (bitwise-identical state). Double-buffered s_c -> 1 barrier/layer.
// Rare ns>64 path keeps a second row per lane (uniform branch).
// ---------------------------------------------------------------------------
__global__ __launch_bounds__(BLK) void encoder_kernel(
    const float* __restrict__ x,
    const float* __restrict__ mp,
    const float* __restrict__ Wf,
    const float* __restrict__ bfv,
    const float* __restrict__ g1,
    const float* __restrict__ b1,
    const float* __restrict__ g2,
    const float* __restrict__ b2,
    float* __restrict__ out)
{
  const int wv   = threadIdx.x >> 6;     // head
  const int lane = threadIdx.x & 63;
  const int b    = blockIdx.x;

  __shared__ float s_mp[1920];           // M then P, rows [5][8]
  __shared__ float s_st[SCR][8];         // compacted state (setup + final only)
  __shared__ int   s_cidx[NTOK];
  __shared__ float s_c[2*NH*SCR*7];      // per-head contribution, stride 7

  for (int r = threadIdx.x; r < 480; r += BLK)
    ((float4*)s_mp)[r] = ((const float4*)mp)[r];

  // ---- setup: ballot compaction (all waves redundant; wave 0 writes) ----
  const float* xb = x + b*300;
  const int t1 = lane, t2 = lane + 64;
  float k0a = xb[3*t1], k1a = xb[3*t1+1], k2a = xb[3*t1+2];
  bool m1 = (k2a > 0.f);
  float k0b=0.f, k1b=0.f, k2b=0.f; bool m2=false;
  if (t2 < NTOK) { k0b=xb[3*t2]; k1b=xb[3*t2+1]; k2b=xb[3*t2+2]; m2=(k2b>0.f); }
  unsigned long long bm1 = __ballot(m1);
  unsigned long long bm2 = __ballot(m2);
  const int pc1 = __popcll(bm1);
  const int nm  = pc1 + __popcll(bm2);   // unmasked count (uniform)
  const int ns  = nm + 1;                // + rep slot
  if (wv == 0) {
    unsigned long long below = (lane==0) ? 0ull : ((1ull<<lane)-1ull);
    int p1 = __popcll(bm1 & below);
    int p2 = pc1 + __popcll(bm2 & below);
    if (m1) {
      *(float4*)(&s_st[p1][0]) = make_float4(k0a,k1a,k2a,sinf((float)t1));
      s_st[p1][4] = cosf((float)t1);
    }
    s_cidx[t1] = m1 ? p1 : nm;
    if (t2 < NTOK) {
      if (m2) {
        *(float4*)(&s_st[p2][0]) = make_float4(k0b,k1b,k2b,sinf((float)t2));
        s_st[p2][4] = cosf((float)t2);
      }
      s_cidx[t2] = m2 ? p2 : nm;
    }
    if (lane == 0) {
      *(float4*)(&s_st[nm][0]) = make_float4(0.f,0.f,0.f,0.f);
      s_st[nm][4] = 0.f;
    }
  }
  __syncthreads();                       // barrier 1 (mp + setup)

  const bool slow = (ns > 64);
  const bool act1 = (lane < ns);
  const bool rep1 = (lane == nm);
  const int  rA   = act1 ? lane : nm;    // clamped (inactive lanes mirror rep)
  const int  rBi  = lane + 64;
  const bool act2 = slow && (rBi < ns);
  const bool rep2 = (rBi == nm);
  const int  rB   = act2 ? rBi : nm;

  float o[5], o2[5] = {0.f,0.f,0.f,0.f,0.f};
  { float4 v = *(const float4*)(&s_st[rA][0]);
    o[0]=v.x; o[1]=v.y; o[2]=v.z; o[3]=v.w; o[4]=s_st[rA][4]; }
  if (slow) {
    float4 v = *(const float4*)(&s_st[rB][0]);
    o2[0]=v.x; o2[1]=v.y; o2[2]=v.z; o2[3]=v.w; o2[4]=s_st[rB][4];
  }

  for (int l = 0; l < NL; ++l) {
    float* cb = s_c + (l & 1)*(NH*SCR*7);
    const float* Mh = s_mp + (l*NH + wv)*40;
    const float* Ph = s_mp + 960 + (l*NH + wv)*40;

    // ---- a = o @ M_h (wave-uniform LDS reads of M, register math) ----
    float aA[5] = {0,0,0,0,0}, aB[5] = {0,0,0,0,0};
    #pragma unroll
    for (int e = 0; e < 5; ++e) {
      float4 mr = *(const float4*)(Mh + e*8); float m4 = Mh[e*8+4];
      aA[0]+=o[e]*mr.x; aA[1]+=o[e]*mr.y; aA[2]+=o[e]*mr.z; aA[3]+=o[e]*mr.w; aA[4]+=o[e]*m4;
      if (slow) {
        aB[0]+=o2[e]*mr.x; aB[1]+=o2[e]*mr.y; aB[2]+=o2[e]*mr.z; aB[3]+=o2[e]*mr.w; aB[4]+=o2[e]*m4;
      }
    }
    #pragma unroll
    for (int e = 0; e < 5; ++e) { aA[e]*=LOG2E; aB[e]*=LOG2E; }

    float wA[5]={0,0,0,0,0}, lsA=0.f;
    float wB[5]={0,0,0,0,0}, lsB=0.f;

    // ---- attention j-loop: v_readlane broadcast, ZERO LDS ----
    if (!slow) {
      #pragma unroll 2
      for (int j = 0; j < nm; ++j) {
        float oj[5];
        #pragma unroll
        for (int e = 0; e < 5; ++e) oj[e] = rdlane(o[e], j);
        float s = aA[0]*oj[0]+aA[1]*oj[1]+aA[2]*oj[2]+aA[3]*oj[3]+aA[4]*oj[4];
        float p = __builtin_amdgcn_exp2f(s);
        p = rep1 ? 1.f : p;
        lsA += p;
        #pragma unroll
        for (int e = 0; e < 5; ++e) wA[e] += p*oj[e];
      }
    } else {
      #pragma unroll 2
      for (int j = 0; j < 64; ++j) {
        float oj[5];
        #pragma unroll
        for (int e = 0; e < 5; ++e) oj[e] = rdlane(o[e], j);
        float sA = aA[0]*oj[0]+aA[1]*oj[1]+aA[2]*oj[2]+aA[3]*oj[3]+aA[4]*oj[4];
        float sB = aB[0]*oj[0]+aB[1]*oj[1]+aB[2]*oj[2]+aB[3]*oj[3]+aB[4]*oj[4];
        float pA = __builtin_amdgcn_exp2f(sA);
        float pB = __builtin_amdgcn_exp2f(sB);
        pA = rep1 ? 1.f : pA;
        pB = rep2 ? 1.f : pB;
        lsA += pA; lsB += pB;
        #pragma unroll
        for (int e = 0; e < 5; ++e) { wA[e] += pA*oj[e]; wB[e] += pB*oj[e]; }
      }
      for (int j = 64; j < nm; ++j) {
        float oj[5];
        #pragma unroll
        for (int e = 0; e < 5; ++e) oj[e] = rdlane(o2[e], j-64);
        float sA = aA[0]*oj[0]+aA[1]*oj[1]+aA[2]*oj[2]+aA[3]*oj[3]+aA[4]*oj[4];
        float sB = aB[0]*oj[0]+aB[1]*oj[1]+aB[2]*oj[2]+aB[3]*oj[3]+aB[4]*oj[4];
        float pA = __builtin_amdgcn_exp2f(sA);
        float pB = __builtin_amdgcn_exp2f(sB);
        pA = rep1 ? 1.f : pA;
        pB = rep2 ? 1.f : pB;
        lsA += pA; lsB += pB;
        #pragma unroll
        for (int e = 0; e < 5; ++e) { wA[e] += pA*oj[e]; wB[e] += pB*oj[e]; }
      }
    }

    // ---- apply own head's P, write 5-float contribution (stride-7) ----
    {
      float wext = rep1 ? (float)(NTOK - nm) : 0.f;
      float inv  = rep1 ? 0.01f : 1.f/lsA;
      float cc[5] = {0,0,0,0,0};
      #pragma unroll
      for (int f = 0; f < 5; ++f) {
        float wn = (wA[f] + wext*o[f]) * inv;
        float4 pr = *(const float4*)(Ph + f*8); float p4 = Ph[f*8+4];
        cc[0]+=wn*pr.x; cc[1]+=wn*pr.y; cc[2]+=wn*pr.z; cc[3]+=wn*pr.w; cc[4]+=wn*p4;
      }
      if (act1) {
        float* dst = cb + (wv*SCR + lane)*7;
        #pragma unroll
        for (int e = 0; e < 5; ++e) dst[e] = cc[e];
      }
    }
    if (slow) {
      float wext = rep2 ? (float)(NTOK - nm) : 0.f;
      float inv  = rep2 ? 0.01f : 1.f/lsB;
      float cc[5] = {0,0,0,0,0};
      #pragma unroll
      for (int f = 0; f < 5; ++f) {
        float wn = (wB[f] + wext*o2[f]) * inv;
        float4 pr = *(const float4*)(Ph + f*8); float p4 = Ph[f*8+4];
        cc[0]+=wn*pr.x; cc[1]+=wn*pr.y; cc[2]+=wn*pr.z; cc[3]+=wn*pr.w; cc[4]+=wn*p4;
      }
      if (act2) {
        float* dst = cb + (wv*SCR + rBi)*7;
        #pragma unroll
        for (int e = 0; e < 5; ++e) dst[e] = cc[e];
      }
    }
    __syncthreads();                     // 1 barrier per layer

    // ---- token pass: redundant in every wave, fixed head order ----
    auto tokpass = [&](float* o_, int row) {
      float sum[5] = {0,0,0,0,0};
      #pragma unroll
      for (int h = 0; h < NH; ++h) {
        const float* src = cb + (h*SCR + row)*7;
        #pragma unroll
        for (int e = 0; e < 5; ++e) sum[e] += src[e];
      }
      float y[5];
      #pragma unroll
      for (int e = 0; e < 5; ++e) y[e] = o_[e] + sum[e];
      float mu = 0.2f*(y[0]+y[1]+y[2]+y[3]+y[4]);
      float var = 0.f;
      #pragma unroll
      for (int e = 0; e < 5; ++e) { float d = y[e]-mu; var += d*d; }
      var *= 0.2f;
      float inv1 = 1.f/sqrtf(var + 1e-5f);
      float ln1[5];
      #pragma unroll
      for (int e = 0; e < 5; ++e) ln1[e] = (y[e]-mu)*inv1*g1[l*5+e] + b1[l*5+e];
      float rv[5];
      #pragma unroll
      for (int e = 0; e < 5; ++e) {
        float acc = bfv[l*5+e];
        #pragma unroll
        for (int f = 0; f < 5; ++f) acc += ln1[f]*Wf[(l*5+e)*5+f];
        acc = acc > 0.f ? acc : 0.f;
        rv[e] = acc + ln1[e];
      }
      float mu2 = 0.2f*(rv[0]+rv[1]+rv[2]+rv[3]+rv[4]);
      float var2 = 0.f;
      #pragma unroll
      for (int e = 0; e < 5; ++e) { float d = rv[e]-mu2; var2 += d*d; }
      var2 *= 0.2f;
      float inv2 = 1.f/sqrtf(var2 + 1e-5f);
      #pragma unroll
      for (int e = 0; e < 5; ++e) o_[e] = (rv[e]-mu2)*inv2*g2[l*5+e] + b2[l*5+e];
    };
    tokpass(o, rA);
    if (slow) tokpass(o2, rB);
    // no barrier here: next layer writes the OTHER s_c buffer
  }

  // ---- wave 0 materializes final state; coalesced expand ----
  if (wv == 0) {
    if (act1) {
      *(float4*)(&s_st[lane][0]) = make_float4(o[0],o[1],o[2],o[3]);
      s_st[lane][4] = o[4];
    }
    if (act2) {
      *(float4*)(&s_st[rBi][0]) = make_float4(o2[0],o2[1],o2[2],o2[3]);
      s_st[rBi][4] = o2[4];
    }
  }
  __syncthreads();
  const int obase = b*(NTOK*EDIM);
  for (int idx = threadIdx.x; idx < NTOK*EDIM; idx += BLK) {
    int tok = idx / 5;
    int e = idx - tok*5;
    out[obase + idx] = s_st[s_cidx[tok]][e];
  }
}

extern "C" void kernel_launch(void* const* d_in, const int* in_sizes, int n_in,
                              void* d_out, int out_size, void* d_ws, size_t ws_size,
                              hipStream_t stream) {
  const float* x  = (const float*)d_in[0];
  const float* Wq = (const float*)d_in[1];
  const float* Wk = (const float*)d_in[2];
  const float* Wv = (const float*)d_in[3];
  const float* Wo = (const float*)d_in[4];
  const float* Wf = (const float*)d_in[5];
  const float* bf = (const float*)d_in[6];
  const float* g1 = (const float*)d_in[7];
  const float* b1 = (const float*)d_in[8];
  const float* g2 = (const float*)d_in[9];
  const float* b2 = (const float*)d_in[10];
  float* outp = (float*)d_out;
  float* mp   = (float*)d_ws;   // 1920 floats

  precompute_mp<<<24, 64, 0, stream>>>(Wq, Wk, Wv, Wo, mp);
  encoder_kernel<<<1024, BLK, 0, stream>>>(x, mp, Wf, bf, g1, b1, g2, b2, outp);
}